// Round 6
// baseline (173.129 us; speedup 1.0000x reference)
//
#include <hip/hip_runtime.h>

// GCN 2-layer, N=200000, E=3200000.
// R19: R18 structure, minus NT hints, plus DEGREE-SORTED node permutation.
// k_build counting-sorts each bucket's 512 nodes by degree (LDS hist[64] +
// wave scan + cursor) -> perm16[bucket*512+rank]=local_id. agg kernels walk
// nodes in rank order: each wave gets 64 degree-homogeneous nodes, so the
// gather loop runs ~mean(16) iterations instead of ~max(26-28) — attacks
// wave divergence, the last untested mechanism in the agg loops.
// 4 launches: bin -> build -> agg1 -> agg2 (+tiny gcur memset).

#define BSE   512     // bin block size
#define CH    16384   // edges per bin block (LDS stage = 64KB)
#define NBW   512     // nodes per bucket
#define SH    9       // log2(NBW)
#define NB    391     // buckets = ceil(200000/512)
#define FCAP  10752   // slab capacity (valid mean 8184 + pad mean ~1470, +10 sigma)
#define BSB   512     // build block size
#define RSTG4 ((FCAP + 4 * BSB - 1) / (4 * BSB))   // 6 x uint4 staging regs
#define NOEDGE 0xFFFFFFFFu

typedef unsigned u32x4 __attribute__((ext_vector_type(4)));

// P1: bin. count -> scan+reserve -> LDS counting sort -> linear coalesced
// write-out -> sentinel-fill pad. (unchanged from R16)
__global__ void k_bin(const int* __restrict__ src, const int* __restrict__ dst,
                      int E, unsigned* __restrict__ gcur,
                      unsigned* __restrict__ epack) {
    __shared__ unsigned stage[CH];       // 64KB: bucket-sorted chunk
    __shared__ unsigned cnt[NB];
    __shared__ unsigned ofs[NB + 1];     // exclusive scan of cnt
    __shared__ unsigned curp[NB];        // LDS scatter cursor
    __shared__ unsigned gbase[NB];       // global slab base per bucket
    __shared__ unsigned wsum[BSE / 64];
    const int b = blockIdx.x, t = threadIdx.x;
    for (int i = t; i < NB; i += BSE) cnt[i] = 0;
    __syncthreads();
    const int lo = b * CH, hi = min(E, lo + CH);
    const int n = hi - lo;
    const int aligned = n & ~3;
    // pass 1: count per bucket
    for (int i = 4 * t; i + 3 < n; i += 4 * BSE) {
        int4 d4 = *(const int4*)(dst + lo + i);
        atomicAdd(&cnt[((unsigned)d4.x) >> SH], 1u);
        atomicAdd(&cnt[((unsigned)d4.y) >> SH], 1u);
        atomicAdd(&cnt[((unsigned)d4.z) >> SH], 1u);
        atomicAdd(&cnt[((unsigned)d4.w) >> SH], 1u);
    }
    for (int i = aligned + t; i < n; i += BSE)
        atomicAdd(&cnt[((unsigned)dst[lo + i]) >> SH], 1u);
    __syncthreads();
    // block scan of bucket counts (shuffle scan, 512 lanes covers NB=391)
    const unsigned c = (t < NB) ? cnt[t] : 0u;
    unsigned v = c;
    #pragma unroll
    for (int off = 1; off < 64; off <<= 1) {
        unsigned u = __shfl_up(v, off);
        if ((t & 63) >= off) v += u;
    }
    if ((t & 63) == 63) wsum[t >> 6] = v;
    __syncthreads();
    if (t < BSE / 64) {
        unsigned w = wsum[t];
        #pragma unroll
        for (int off = 1; off < BSE / 64; off <<= 1) {
            unsigned u = __shfl_up(w, off);
            if (t >= off) w += u;
        }
        wsum[t] = w;
    }
    __syncthreads();
    const unsigned incl = v + ((t >> 6) ? wsum[(t >> 6) - 1] : 0u);
    const unsigned excl = incl - c;
    if (t < NB) {
        ofs[t] = excl;
        curp[t] = excl;
        unsigned pad = (c + 15u) & ~15u;             // 64B-aligned reservation
        unsigned o = pad ? atomicAdd(&gcur[t], pad) : 0u;
        gbase[t] = (unsigned)t * FCAP + o;
    }
    if (t == NB - 1) ofs[NB] = incl;                 // = n
    __syncthreads();
    // pass 2: counting-sort edges into LDS
    for (int i = 4 * t; i + 3 < n; i += 4 * BSE) {
        int4 d4 = *(const int4*)(dst + lo + i);
        int4 s4 = *(const int4*)(src + lo + i);
        unsigned k0 = ((unsigned)d4.x) >> SH, k1 = ((unsigned)d4.y) >> SH;
        unsigned k2 = ((unsigned)d4.z) >> SH, k3 = ((unsigned)d4.w) >> SH;
        unsigned p0 = atomicAdd(&curp[k0], 1u);
        unsigned p1 = atomicAdd(&curp[k1], 1u);
        unsigned p2 = atomicAdd(&curp[k2], 1u);
        unsigned p3 = atomicAdd(&curp[k3], 1u);
        stage[p0] = ((unsigned)s4.x << SH) | (((unsigned)d4.x) & (NBW - 1u));
        stage[p1] = ((unsigned)s4.y << SH) | (((unsigned)d4.y) & (NBW - 1u));
        stage[p2] = ((unsigned)s4.z << SH) | (((unsigned)d4.z) & (NBW - 1u));
        stage[p3] = ((unsigned)s4.w << SH) | (((unsigned)d4.w) & (NBW - 1u));
    }
    for (int i = aligned + t; i < n; i += BSE) {
        unsigned d = (unsigned)dst[lo + i];
        unsigned k = d >> SH;
        unsigned pos = atomicAdd(&curp[k], 1u);
        stage[pos] = ((unsigned)src[lo + i] << SH) | (d & (NBW - 1u));
    }
    __syncthreads();
    // pass 3: linear write-out (bucket by binary search over scanned offsets)
    for (int p0 = 4 * t; p0 < n; p0 += 4 * BSE) {
        unsigned k = 0;                              // largest k: ofs[k] <= p0
        #pragma unroll
        for (unsigned s = 256; s; s >>= 1) {
            unsigned cand = k + s;
            if (cand <= NB && ofs[cand] <= (unsigned)p0) k = cand;
        }
        #pragma unroll
        for (int j = 0; j < 4; ++j) {
            int p = p0 + j;
            if (p >= n) break;
            while (ofs[k + 1] <= (unsigned)p) ++k;   // rare boundary advance
            unsigned addr = gbase[k] + ((unsigned)p - ofs[k]);
            if (addr < (k + 1u) * FCAP) epack[addr] = stage[p];
        }
    }
    // sentinel-fill the pad of each cell (disjoint regions, no sync needed)
    for (int i = t; i < NB; i += BSE) {
        unsigned s = gbase[i] + cnt[i];
        unsigned e = gbase[i] + ((cnt[i] + 15u) & ~15u);
        unsigned kend = ((unsigned)i + 1u) * FCAP;
        if (e > kend) e = kend;
        for (unsigned p = s; p < e; ++p) epack[p] = NOEDGE;
    }
}

// P2: per bucket — stage slab into registers (6x 16B loads, static indexed),
// count per node, wave-shuffle scan of PADDED counts (16B-aligned segments),
// counting sort into LDS, coalesced writeback. Also: counting-sort the 512
// nodes by degree -> perm16 (degree-homogeneous waves for agg kernels).
// Emits meta = excl|(c<<14), perm16, x_scaled.
__global__ void k_build(unsigned* __restrict__ epack, const unsigned* __restrict__ gcur,
                        const float* __restrict__ x,
                        unsigned* __restrict__ meta, unsigned short* __restrict__ perm16,
                        float* __restrict__ x_scaled, int N) {
    __shared__ unsigned stage[FCAP];     // sorted src lists only
    __shared__ unsigned cnt[BSB];
    __shared__ unsigned cur[BSB];
    __shared__ unsigned wsum[BSB / 64];
    __shared__ unsigned hist[64];        // degree histogram (bin = min(c,63))
    __shared__ unsigned s_lenv;
    const int k = blockIdx.x, t = threadIdx.x;     // 512 threads
    const unsigned base = (unsigned)k * FCAP;
    const int len = min((int)gcur[k], FCAP);       // multiple of 16
    const int len4 = len >> 2;
    const u32x4* ep4 = (const u32x4*)(epack + base);
    u32x4 r4[RSTG4];                               // 24 VGPRs, static indexed
    #pragma unroll
    for (int j = 0; j < RSTG4; ++j) {
        int i4 = t + j * BSB;                      // coalesced 16B loads
        if (i4 < len4) r4[j] = ep4[i4];
        else           r4[j] = (u32x4){NOEDGE, NOEDGE, NOEDGE, NOEDGE};
    }
    cnt[t] = 0;
    if (t < 64) hist[t] = 0;
    __syncthreads();
    #pragma unroll
    for (int j = 0; j < RSTG4; ++j) {
        #pragma unroll
        for (int e = 0; e < 4; ++e) {
            unsigned p = r4[j][e];
            if (p != NOEDGE) atomicAdd(&cnt[p & (NBW - 1u)], 1u);
        }
    }
    __syncthreads();
    const unsigned c  = cnt[t];
    const unsigned dbin = min(c, 63u);
    atomicAdd(&hist[dbin], 1u);                    // degree histogram
    const unsigned cp = (c + 3u) & ~3u;            // 16B-aligned segment
    unsigned v = cp;                               // inclusive wave-scan (64)
    #pragma unroll
    for (int off = 1; off < 64; off <<= 1) {
        unsigned u = __shfl_up(v, off);
        if ((t & 63) >= off) v += u;
    }
    if ((t & 63) == 63) wsum[t >> 6] = v;
    __syncthreads();
    if (t < BSB / 64) {                            // scan the 8 wave sums
        unsigned w = wsum[t];
        #pragma unroll
        for (int off = 1; off < BSB / 64; off <<= 1) {
            unsigned u = __shfl_up(w, off);
            if (t >= off) w += u;
        }
        wsum[t] = w;                               // inclusive
    }
    if (t < 64) {                                  // exclusive scan of hist
        unsigned h = hist[t], s = h;
        #pragma unroll
        for (int off = 1; off < 64; off <<= 1) {
            unsigned u = __shfl_up(s, off);
            if (t >= off) s += u;
        }
        hist[t] = s - h;                           // exclusive; reused as cursor
    }
    __syncthreads();
    const unsigned incl = v + ((t >> 6) ? wsum[(t >> 6) - 1] : 0u);
    const unsigned excl = incl - cp;               // multiple of 4
    cur[t] = excl;
    if (t == BSB - 1) s_lenv = incl;               // padded edge count
    const unsigned rank = atomicAdd(&hist[dbin], 1u);
    perm16[(unsigned)k * NBW + rank] = (unsigned short)t;
    const int node = k * NBW + t;
    if (node < N) {
        meta[node] = excl | (c << 14);             // excl<2^14 (mult of 4), c<2^14
        float di = rsqrtf((float)(c + 1u));        // +1: self loop
        float4 xv = ((const float4*)x)[node];
        ((float4*)x_scaled)[node] = make_float4(xv.x * di, xv.y * di, xv.z * di, xv.w * di);
    }
    __syncthreads();
    #pragma unroll
    for (int j = 0; j < RSTG4; ++j) {
        #pragma unroll
        for (int e = 0; e < 4; ++e) {
            unsigned p = r4[j][e];
            if (p != NOEDGE) {
                unsigned pos = atomicAdd(&cur[p & (NBW - 1u)], 1u);
                if (pos < FCAP) stage[pos] = p >> SH;  // sorted src lists
            }
        }
    }
    __syncthreads();
    const int lenv = min((int)s_lenv, FCAP);       // multiple of 4
    for (int i = 4 * t; i < lenv; i += 4 * BSB)    // coalesced writeback
        *(int4*)(epack + base + i) = *(const int4*)&stage[i];
}

// P3: pull-mode layer-1 aggregation + fused node math. Nodes walked in
// degree-rank order (perm16): degree-homogeneous waves, minimal divergence.
__global__ void k_agg1(const unsigned* __restrict__ esorted, const unsigned* __restrict__ meta,
                       const unsigned short* __restrict__ perm16,
                       const float* __restrict__ x_scaled,
                       const float* __restrict__ W1, const float* __restrict__ b1,
                       const float* __restrict__ W2,
                       float* __restrict__ z_scaled, int N) {
    int r = blockIdx.x * blockDim.x + threadIdx.x;
    if (r >= NB * NBW) return;
    int b = r >> SH;
    int node = (b << SH) + perm16[r];
    if (node >= N) return;
    unsigned m = meta[node];
    unsigned c = m >> 14;
    unsigned lo = (unsigned)b * FCAP + (m & 16383u);   // 16B-aligned
    unsigned hi = lo + c;
    float di = rsqrtf((float)(c + 1u));
    const float4* xs4 = (const float4*)x_scaled;
    float4 a0 = xs4[node];                          // self loop
    float4 a1 = make_float4(0.f, 0.f, 0.f, 0.f);
    float4 a2 = make_float4(0.f, 0.f, 0.f, 0.f);
    float4 a3 = make_float4(0.f, 0.f, 0.f, 0.f);
    unsigned i = lo;
    for (; i + 7 < hi; i += 8) {                    // 8 gathers in flight
        u32x4 e0 = *(const u32x4*)(esorted + i);
        u32x4 e1 = *(const u32x4*)(esorted + i + 4);
        float4 v0 = xs4[e0[0]], v1 = xs4[e0[1]], v2 = xs4[e0[2]], v3 = xs4[e0[3]];
        float4 v4 = xs4[e1[0]], v5 = xs4[e1[1]], v6 = xs4[e1[2]], v7 = xs4[e1[3]];
        a0.x += v0.x; a0.y += v0.y; a0.z += v0.z; a0.w += v0.w;
        a1.x += v1.x; a1.y += v1.y; a1.z += v1.z; a1.w += v1.w;
        a2.x += v2.x; a2.y += v2.y; a2.z += v2.z; a2.w += v2.w;
        a3.x += v3.x; a3.y += v3.y; a3.z += v3.z; a3.w += v3.w;
        a0.x += v4.x; a0.y += v4.y; a0.z += v4.z; a0.w += v4.w;
        a1.x += v5.x; a1.y += v5.y; a1.z += v5.z; a1.w += v5.w;
        a2.x += v6.x; a2.y += v6.y; a2.z += v6.z; a2.w += v6.w;
        a3.x += v7.x; a3.y += v7.y; a3.z += v7.z; a3.w += v7.w;
    }
    if (i + 3 < hi) {                               // one 4-wide step
        u32x4 e0 = *(const u32x4*)(esorted + i);
        float4 v0 = xs4[e0[0]], v1 = xs4[e0[1]], v2 = xs4[e0[2]], v3 = xs4[e0[3]];
        a0.x += v0.x; a0.y += v0.y; a0.z += v0.z; a0.w += v0.w;
        a1.x += v1.x; a1.y += v1.y; a1.z += v1.z; a1.w += v1.w;
        a2.x += v2.x; a2.y += v2.y; a2.z += v2.z; a2.w += v2.w;
        a3.x += v3.x; a3.y += v3.y; a3.z += v3.z; a3.w += v3.w;
        i += 4;
    }
    for (; i < hi; ++i) {
        float4 v = xs4[esorted[i]];
        a0.x += v.x; a0.y += v.y; a0.z += v.z; a0.w += v.w;
    }
    float p0 = di * (a0.x + a1.x + a2.x + a3.x);
    float p1 = di * (a0.y + a1.y + a2.y + a3.y);
    float p2 = di * (a0.z + a1.z + a2.z + a3.z);
    float p3 = di * (a0.w + a1.w + a2.w + a3.w);
    float z = 0.0f;
    #pragma unroll
    for (int cc = 0; cc < 16; ++cc) {
        float h1 = p0 * W1[0 * 16 + cc] + p1 * W1[1 * 16 + cc]
                 + p2 * W1[2 * 16 + cc] + p3 * W1[3 * 16 + cc] + b1[cc];
        h1 = fmaxf(h1, 0.0f);
        z += h1 * W2[cc];
    }
    z_scaled[node] = z * di;
}

// P4: pull-mode layer-2 aggregation, degree-rank order.
__global__ void k_agg2(const unsigned* __restrict__ esorted, const unsigned* __restrict__ meta,
                       const unsigned short* __restrict__ perm16,
                       const float* __restrict__ z_scaled,
                       const float* __restrict__ b2, float* __restrict__ out, int N) {
    int r = blockIdx.x * blockDim.x + threadIdx.x;
    if (r >= NB * NBW) return;
    int b = r >> SH;
    int node = (b << SH) + perm16[r];
    if (node >= N) return;
    unsigned m = meta[node];
    unsigned c = m >> 14;
    unsigned lo = (unsigned)b * FCAP + (m & 16383u);
    unsigned hi = lo + c;
    float di = rsqrtf((float)(c + 1u));
    float a0 = z_scaled[node], a1 = 0.f, a2 = 0.f, a3 = 0.f;  // self loop in a0
    unsigned i = lo;
    for (; i + 7 < hi; i += 8) {
        u32x4 e0 = *(const u32x4*)(esorted + i);
        u32x4 e1 = *(const u32x4*)(esorted + i + 4);
        a0 += z_scaled[e0[0]]; a1 += z_scaled[e0[1]];
        a2 += z_scaled[e0[2]]; a3 += z_scaled[e0[3]];
        a0 += z_scaled[e1[0]]; a1 += z_scaled[e1[1]];
        a2 += z_scaled[e1[2]]; a3 += z_scaled[e1[3]];
    }
    if (i + 3 < hi) {
        u32x4 e0 = *(const u32x4*)(esorted + i);
        a0 += z_scaled[e0[0]]; a1 += z_scaled[e0[1]];
        a2 += z_scaled[e0[2]]; a3 += z_scaled[e0[3]];
        i += 4;
    }
    for (; i < hi; ++i) a0 += z_scaled[esorted[i]];
    out[node] = di * (a0 + a1 + a2 + a3) + b2[0];
}

extern "C" void kernel_launch(void* const* d_in, const int* in_sizes, int n_in,
                              void* d_out, int out_size, void* d_ws, size_t ws_size,
                              hipStream_t stream) {
    const float* x  = (const float*)d_in[0];
    const int*   ei = (const int*)d_in[1];   // [2, E] as int32
    const float* W1 = (const float*)d_in[2];
    const float* b1 = (const float*)d_in[3];
    const float* W2 = (const float*)d_in[4];
    const float* b2 = (const float*)d_in[5];

    const int N = in_sizes[0] / 4;
    const int E = in_sizes[1] / 2;
    const int* src = ei;
    const int* dst = ei + E;
    const int NA = (E + CH - 1) / CH;        // 196

    // Workspace (~20 MB): gcur | epack[NB*FCAP] | meta[N] | perm16[NB*NBW] |
    //   x_scaled[N*4] | z_scaled[N]
    char* ws = (char*)d_ws;
    unsigned* gcur       = (unsigned*)ws;       ws += 4096;
    unsigned* epack      = (unsigned*)ws;       ws += (size_t)NB * FCAP * 4;
    unsigned* meta       = (unsigned*)ws;       ws += (size_t)N * 4;
    unsigned short* perm = (unsigned short*)ws; ws += (size_t)NB * NBW * 2;
    float*    x_scaled   = (float*)ws;          ws += (size_t)N * 4 * 4;
    float*    z_scaled   = (float*)ws;          ws += (size_t)N * 4;
    float* out = (float*)d_out;

    const int NR = NB * NBW;                 // 200192 rank slots
    hipMemsetAsync(gcur, 0, NB * sizeof(unsigned), stream);
    k_bin  <<<NA, BSE, 0, stream>>>(src, dst, E, gcur, epack);
    k_build<<<NB, BSB, 0, stream>>>(epack, gcur, x, meta, perm, x_scaled, N);
    k_agg1 <<<(NR + 255) / 256, 256, 0, stream>>>(epack, meta, perm, x_scaled,
                                                  W1, b1, W2, z_scaled, N);
    k_agg2 <<<(NR + 255) / 256, 256, 0, stream>>>(epack, meta, perm, z_scaled,
                                                  b2, out, N);
}